// Round 6
// baseline (76.527 us; speedup 1.0000x reference)
//
#include <hip/hip_runtime.h>
#include <math.h>

// out[b,c] = tanh( sum_{hw} x[b,c,h,w] * W[c,h,w] + bias[c] )
// x: [B=4096, C=512, 7, 7] f32; each (b,c) row = 49 contiguous floats.
//
// R6 = R4 zero-barrier DMA double-buffer + NON-TEMPORAL policy:
//  - 1-wave (64-thread) blocks; 64-row tile = 12544 B; double-buffered LDS.
//  - __builtin_amdgcn_global_load_lds(..., aux=2): CPol NT bit (gfx94x/gfx950
//    encoding: bit0=SC0, bit1=NT) -> read-once stream bypasses L2/L3
//    allocation (R5 proved nt is worth +13% on this kernel).
//  - Counted s_waitcnt vmcnt(13) only waits on the PREVIOUS tile's 13 DMA
//    loads; next tile's stay in flight. No __syncthreads (1 wave/block).
//  - Output store is nontemporal too (write-once, never re-read).
//  - W row + bias in registers (GRID % 8 == 0 => c loop-invariant).

constexpr int K    = 49;        // 7*7
constexpr int TPB  = 64;        // 1 wave per block
constexpr int TILE = TPB * K;   // 3136 floats = 12544 B
constexpr int GRID = 2048;      // 32768 tiles / 2048 = 16 iters, GRID%8==0

__global__ __launch_bounds__(64) void WGP_84018150245011_kernel(
    const float* __restrict__ x,
    const float* __restrict__ W,
    const float* __restrict__ bias,
    float* __restrict__ out,
    int iters) {
  __shared__ float xs[2][TILE];

  const int lane = threadIdx.x;

  // tile t of this block: t % 8 == blockIdx.x % 8, so c = (t*64+lane) % 512
  // = ((bid&7)<<6)|lane is loop-invariant.
  const int c = ((blockIdx.x & 7) << 6) | lane;

  float w[K];
  const float* __restrict__ wr = W + c * K;
#pragma unroll
  for (int k = 0; k < K; ++k) w[k] = wr[k];
  const float bi = bias[c];

  // Async-stage one tile into xs[buf] with NT cache policy (aux=2).
  auto stage = [&](int t, int buf) {
    const float* src = x + (size_t)t * TILE;
#pragma unroll
    for (int j = 0; j < 12; ++j) {
      __builtin_amdgcn_global_load_lds(
          (const __attribute__((address_space(1))) unsigned int*)(src + j * 256 + lane * 4),
          (__attribute__((address_space(3))) unsigned int*)(&xs[buf][j * 256]),
          16, 0, 2 /* CPol::NT */);
    }
    __builtin_amdgcn_global_load_lds(
        (const __attribute__((address_space(1))) unsigned int*)(src + 3072 + lane),
        (__attribute__((address_space(3))) unsigned int*)(&xs[buf][3072]),
        4, 0, 2 /* CPol::NT */);
  };

  auto compute = [&](int buf, int t) {
    const float* xr = &xs[buf][lane * K];  // stride 49 -> bank stride 17, conflict-free
    float s = bi;
#pragma unroll
    for (int k = 0; k < K; ++k) s = fmaf(xr[k], w[k], s);
    __builtin_nontemporal_store(tanhf(s), &out[(size_t)t * TPB + lane]);
  };

  int t   = blockIdx.x;
  int buf = 0;
  stage(t, 0);  // prologue: 13 DMA loads in flight

#pragma unroll 1
  for (int i = 1; i < iters; ++i) {
    const int tn = t + GRID;
    stage(tn, buf ^ 1);                               // +13 issues
    asm volatile("s_waitcnt vmcnt(13)" ::: "memory"); // prev tile done; next in flight
    compute(buf, t);
    buf ^= 1;
    t = tn;
  }
  asm volatile("s_waitcnt vmcnt(0)" ::: "memory");    // epilogue drain
  compute(buf, t);
}

extern "C" void kernel_launch(void* const* d_in, const int* in_sizes, int n_in,
                              void* d_out, int out_size, void* d_ws, size_t ws_size,
                              hipStream_t stream) {
  const float* x    = (const float*)d_in[0];
  const float* W    = (const float*)d_in[1];
  const float* bias = (const float*)d_in[2];
  float* out        = (float*)d_out;

  const int n_rows  = in_sizes[0] / K;   // B*C = 2,097,152
  const int n_tiles = n_rows / TPB;      // 32768
  const int iters   = n_tiles / GRID;    // 16 (exact)

  WGP_84018150245011_kernel<<<GRID, TPB, 0, stream>>>(x, W, bias, out, iters);
}